// Round 4
// baseline (251.793 us; speedup 1.0000x reference)
//
#include <hip/hip_runtime.h>

#define C_  8
#define NQ_ 16
#define NK_ 32
#define B_  128
#define D_  128
#define E_  512
#define H_  8
#define A_  64
#define O_  64

typedef __attribute__((ext_vector_type(4))) float f32x4;
typedef __attribute__((ext_vector_type(8))) short bf16x8;
typedef __attribute__((ext_vector_type(4))) short bf16x4;

__device__ __forceinline__ short f2bf(float f) {
    union { float f; unsigned u; } v; v.f = f;
    unsigned r = v.u + 0x7fffu + ((v.u >> 16) & 1u);
    return (short)(r >> 16);
}

// ---------------------------------------------------------------------------
// Kernel 1: fused PE + per-(c,n) QKV projections.
// grid = 640 units, 512 thr (8 waves). Full 128x512 tile per block, K-step 32.
// B staging reads FULL 2KB W rows (e = tid across 8 waves) -> 100% DRAM row
// utilization, vs 25% with the old e_blk split. Output (c,b,n,e).
// ---------------------------------------------------------------------------
__global__ __launch_bounds__(512) void qkv_proj_kernel(
    const float* __restrict__ qin, const float* __restrict__ kin,
    const float* __restrict__ Wq, const float* __restrict__ Wk,
    const float* __restrict__ Wv,
    short* __restrict__ wsq, short* __restrict__ wsk, short* __restrict__ wsv)
{
    __shared__ __align__(16) short Alds[B_][40];    // [b][k], K-step 32 pad->40
    __shared__ __align__(16) short Blds[E_][40];    // [e][k] transposed W
    __shared__ float pe_buf[D_];

    const int tid  = threadIdx.x;
    const int unit = blockIdx.x;

    const float* X; const float* W; short* Y; int n; size_t bpitch;
    if (unit < C_ * NQ_) {
        const int c = unit >> 4;
        n = unit & 15;
        X = qin + (size_t)unit * B_ * D_;
        W = Wq  + (size_t)unit * D_ * E_;
        Y = wsq + (size_t)c * B_ * NQ_ * E_ + (size_t)n * E_;
        bpitch = (size_t)NQ_ * E_;
    } else if (unit < C_ * (NQ_ + NK_)) {
        const int u = unit - C_ * NQ_;
        const int c = u >> 5;
        n = u & 31;
        X = kin + (size_t)u * B_ * D_;
        W = Wk  + (size_t)u * D_ * E_;
        Y = wsk + (size_t)c * B_ * NK_ * E_ + (size_t)n * E_;
        bpitch = (size_t)NK_ * E_;
    } else {
        const int u = unit - C_ * (NQ_ + NK_);
        const int c = u >> 5;
        n = u & 31;
        X = kin + (size_t)u * B_ * D_;
        W = Wv  + (size_t)u * D_ * E_;
        Y = wsv + (size_t)c * B_ * NK_ * E_ + (size_t)n * E_;
        bpitch = (size_t)NK_ * E_;
    }

    if (tid < D_) {
        const int d = tid;
        const float freq = expf((float)(d & ~1) * (-9.210340371976184f / (float)D_));
        const float arg  = (float)n * freq;
        pe_buf[d] = (d & 1) ? cosf(arg) : sinf(arg);
    }
    __syncthreads();

    const int wv   = tid >> 6;
    const int lane = tid & 63;
    const int lr   = lane & 15;
    const int quad = lane >> 4;
    const int wrow = (wv >> 2) * 64;   // 0 or 64   (b rows)
    const int wcol = (wv & 3) * 128;   // e columns

    f32x4 acc[4][8];
    #pragma unroll
    for (int m = 0; m < 4; ++m)
        #pragma unroll
        for (int nf = 0; nf < 8; ++nf)
            acc[m][nf] = (f32x4){0.f, 0.f, 0.f, 0.f};

    for (int k0 = 0; k0 < D_; k0 += 32) {
        // --- A: 128 rows x 32 k fp32, 2 float4/thread, fully coalesced ---
        f32x4 a_raw[2];
        #pragma unroll
        for (int i = 0; i < 2; ++i) {
            const int id  = tid + 512 * i;
            const int row = id >> 3;
            const int seg = id & 7;
            a_raw[i] = *(const f32x4*)(X + (size_t)row * D_ + k0 + seg * 4);
        }
        // --- B: 32 k-rows x 512 e fp32; e = tid; full 2KB rows streamed ---
        float b_raw[32];
        const float* bsrc = W + (size_t)k0 * E_ + tid;
        #pragma unroll
        for (int kk = 0; kk < 32; ++kk)
            b_raw[kk] = bsrc[(size_t)kk * E_];

        #pragma unroll
        for (int i = 0; i < 2; ++i) {
            const int id  = tid + 512 * i;
            const int row = id >> 3;
            const int seg = id & 7;
            bf16x4 v;
            #pragma unroll
            for (int j = 0; j < 4; ++j)
                v[j] = f2bf(a_raw[i][j] + pe_buf[k0 + seg * 4 + j]);
            *(bf16x4*)&Alds[row][seg * 4] = v;
        }
        #pragma unroll
        for (int g = 0; g < 4; ++g) {
            bf16x8 v;
            #pragma unroll
            for (int j = 0; j < 8; ++j)
                v[j] = f2bf(b_raw[g * 8 + j]);
            *(bf16x8*)&Blds[tid][g * 8] = v;
        }
        __syncthreads();

        bf16x8 af[4], bfr[8];
        #pragma unroll
        for (int m = 0; m < 4; ++m)
            af[m] = *(const bf16x8*)&Alds[wrow + m * 16 + lr][quad * 8];
        #pragma unroll
        for (int nf = 0; nf < 8; ++nf)
            bfr[nf] = *(const bf16x8*)&Blds[wcol + nf * 16 + lr][quad * 8];
        #pragma unroll
        for (int m = 0; m < 4; ++m)
            #pragma unroll
            for (int nf = 0; nf < 8; ++nf)
                acc[m][nf] = __builtin_amdgcn_mfma_f32_16x16x32_bf16(
                    af[m], bfr[nf], acc[m][nf], 0, 0, 0);
        __syncthreads();
    }

    // epilogue: each b-row gets a full 1KB contiguous cluster across waves
    #pragma unroll
    for (int m = 0; m < 4; ++m)
        #pragma unroll
        for (int nf = 0; nf < 8; ++nf)
            #pragma unroll
            for (int r = 0; r < 4; ++r) {
                const int row = wrow + m * 16 + quad * 4 + r;   // b
                const int col = wcol + nf * 16 + lr;            // e
                Y[(size_t)row * bpitch + col] = f2bf(acc[m][nf][r]);
            }
}

// ---------------------------------------------------------------------------
// Kernel 2: attention. Block = (c, b, head-half). Reads from (c,b,n,e)
// workspace (contiguous 80KB region). Stores to (c,b,q,e) wso: 8KB cluster.
// ---------------------------------------------------------------------------
__global__ __launch_bounds__(256) void attn_kernel(
    const short* __restrict__ wsq, const short* __restrict__ wsk,
    const short* __restrict__ wsv, short* __restrict__ wso)
{
    __shared__ __align__(16) short Qs[16][264];
    __shared__ __align__(16) short Ks[32][264];
    __shared__ __align__(16) short Vs[32][258];
    __shared__ __align__(16) short Ps[4][16][40];

    const int tid = threadIdx.x;
    const int blk = blockIdx.x;              // ((c*B + b)*2 + hh)
    const int hh  = blk & 1;
    const int b   = (blk >> 1) & (B_ - 1);
    const int c   = blk >> 8;

    const short* qb = wsq + ((size_t)(c * B_ + b) * NQ_) * E_ + hh * 256;
    const short* kb = wsk + ((size_t)(c * B_ + b) * NK_) * E_ + hh * 256;
    const short* vb = wsv + ((size_t)(c * B_ + b) * NK_) * E_ + hh * 256;

    {
        const int nloc = tid >> 5;
        const int ch   = tid & 31;
        #pragma unroll
        for (int i = 0; i < 2; ++i) {
            const int nn = nloc + i * 8;
            *(bf16x8*)&Qs[nn][ch * 8] = *(const bf16x8*)(qb + (size_t)nn * E_ + ch * 8);
        }
        #pragma unroll
        for (int i = 0; i < 4; ++i) {
            const int nn = nloc + i * 8;
            *(bf16x8*)&Ks[nn][ch * 8] = *(const bf16x8*)(kb + (size_t)nn * E_ + ch * 8);
        }
        #pragma unroll
        for (int i = 0; i < 4; ++i) {
            const int nn = nloc + i * 8;
            bf16x8 v = *(const bf16x8*)(vb + (size_t)nn * E_ + ch * 8);
            #pragma unroll
            for (int p = 0; p < 4; ++p)
                *(int*)&Vs[nn][ch * 8 + p * 2] = ((const int*)&v)[p];
        }
    }
    __syncthreads();

    const int wv   = tid >> 6;
    const int lane = tid & 63;
    const int lr   = lane & 15;
    const int quad = lane >> 4;
    const int lcol = wv * 64;

    f32x4 sacc0 = (f32x4){0.f, 0.f, 0.f, 0.f};
    f32x4 sacc1 = (f32x4){0.f, 0.f, 0.f, 0.f};
    #pragma unroll
    for (int ks = 0; ks < 2; ++ks) {
        const int kc = lcol + ks * 32 + quad * 8;
        const bf16x8 aq  = *(const bf16x8*)&Qs[lr][kc];
        const bf16x8 bk0 = *(const bf16x8*)&Ks[lr][kc];
        const bf16x8 bk1 = *(const bf16x8*)&Ks[16 + lr][kc];
        sacc0 = __builtin_amdgcn_mfma_f32_16x16x32_bf16(aq, bk0, sacc0, 0, 0, 0);
        sacc1 = __builtin_amdgcn_mfma_f32_16x16x32_bf16(aq, bk1, sacc1, 0, 0, 0);
    }

    float p0[4], p1[4];
    for (int r = 0; r < 4; ++r) {
        const float v0 = sacc0[r] * 0.125f;
        const float v1 = sacc1[r] * 0.125f;
        float m = fmaxf(v0, v1);
        m = fmaxf(m, __shfl_xor(m, 1));
        m = fmaxf(m, __shfl_xor(m, 2));
        m = fmaxf(m, __shfl_xor(m, 4));
        m = fmaxf(m, __shfl_xor(m, 8));
        const float e0 = __expf(v0 - m);
        const float e1 = __expf(v1 - m);
        float s = e0 + e1;
        s += __shfl_xor(s, 1);
        s += __shfl_xor(s, 2);
        s += __shfl_xor(s, 4);
        s += __shfl_xor(s, 8);
        const float inv = 1.0f / s;
        p0[r] = e0 * inv;
        p1[r] = e1 * inv;
    }

    for (int r = 0; r < 4; ++r) {
        Ps[wv][quad * 4 + r][lr]      = f2bf(p0[r]);
        Ps[wv][quad * 4 + r][16 + lr] = f2bf(p1[r]);
    }
    __syncthreads();
    const bf16x8 ap = *(const bf16x8*)&Ps[wv][lr][quad * 8];

    #pragma unroll
    for (int t = 0; t < 4; ++t) {
        bf16x8 bvv;
        #pragma unroll
        for (int j = 0; j < 8; ++j)
            bvv[j] = Vs[quad * 8 + j][lcol + t * 16 + lr];
        f32x4 oacc = (f32x4){0.f, 0.f, 0.f, 0.f};
        oacc = __builtin_amdgcn_mfma_f32_16x16x32_bf16(ap, bvv, oacc, 0, 0, 0);
        for (int r = 0; r < 4; ++r)
            wso[((size_t)(c * B_ + b) * NQ_ + quad * 4 + r) * E_
                + hh * 256 + lcol + t * 16 + lr] = f2bf(oacc[r]);
    }
}

// ---------------------------------------------------------------------------
// Kernel 3: output projection. 512 blocks = (c,q) x B-half x O-half.
// X (64 rows x 512 e bf16) preloaded to LDS once with full-1KB-row loads;
// K-loop double-buffers only Wp.
// ---------------------------------------------------------------------------
__global__ __launch_bounds__(256) void out_proj_kernel(
    const short* __restrict__ wso, const float* __restrict__ Wp,
    float* __restrict__ out)
{
    __shared__ __align__(16) short Xlds[64][520];
    __shared__ __align__(16) short Wlds[32][72];

    const int tid = threadIdx.x;
    const int blk = blockIdx.x;
    const int cq  = blk >> 2;           // c*NQ + q
    const int bh  = (blk >> 1) & 1;
    const int oh  = blk & 1;
    const int c   = cq >> 4;
    const int qn  = cq & 15;

    const short* Xb = wso + ((size_t)(c * B_ + bh * 64) * NQ_ + qn) * E_;
    const size_t xpitch = (size_t)NQ_ * E_;
    const float* Wb = Wp  + (size_t)cq * E_ * O_ + oh * 32;
    float*       Ob = out + (size_t)cq * B_ * O_ + (size_t)bh * 64 * O_ + oh * 32;

    const int wv   = tid >> 6;
    const int lane = tid & 63;
    const int lr   = lane & 15;
    const int quad = lane >> 4;
    const int o    = tid & 31;
    const int kg   = tid >> 5;   // 0..7

    // ---- preload X: 16 bf16x8 loads/thread, each instr = full 1KB row ----
    {
        bf16x8 xv[16];
        #pragma unroll
        for (int i = 0; i < 16; ++i) {
            const int task = tid + 256 * i;
            const int row  = task >> 6;
            const int ch   = task & 63;
            xv[i] = *(const bf16x8*)(Xb + (size_t)row * xpitch + ch * 8);
        }
        #pragma unroll
        for (int i = 0; i < 16; ++i) {
            const int task = tid + 256 * i;
            *(bf16x8*)&Xlds[task >> 6][(task & 63) * 8] = xv[i];
        }
    }

    f32x4 acc[2];
    acc[0] = (f32x4){0.f, 0.f, 0.f, 0.f};
    acc[1] = (f32x4){0.f, 0.f, 0.f, 0.f};

    float wr[2][8];
    auto issueW = [&](int s, int buf) {
        const int k0 = s * 64;
        #pragma unroll
        for (int j = 0; j < 8; ++j)
            wr[buf][j] = Wb[(size_t)(k0 + kg * 8 + j) * O_ + o];
    };

    issueW(0, 0);
    __syncthreads();   // X ready

    #pragma unroll
    for (int s = 0; s < 8; ++s) {
        const int cb = s & 1;
        if (s < 7) issueW(s + 1, cb ^ 1);

        bf16x8 wv8;
        #pragma unroll
        for (int j = 0; j < 8; ++j) wv8[j] = f2bf(wr[cb][j]);
        *(bf16x8*)&Wlds[o][kg * 8] = wv8;
        __syncthreads();

        #pragma unroll
        for (int ks = 0; ks < 2; ++ks) {
            const int kc = s * 64 + ks * 32 + quad * 8;
            const bf16x8 af = *(const bf16x8*)&Xlds[wv * 16 + lr][kc];
            #pragma unroll
            for (int nf = 0; nf < 2; ++nf) {
                const bf16x8 bfr = *(const bf16x8*)&Wlds[nf * 16 + lr][(kc & 63)];
                acc[nf] = __builtin_amdgcn_mfma_f32_16x16x32_bf16(af, bfr, acc[nf], 0, 0, 0);
            }
        }
        __syncthreads();
    }

    #pragma unroll
    for (int nf = 0; nf < 2; ++nf)
        for (int r = 0; r < 4; ++r)
            Ob[(size_t)(wv * 16 + quad * 4 + r) * O_ + nf * 16 + lr] = acc[nf][r];
}

extern "C" void kernel_launch(void* const* d_in, const int* in_sizes, int n_in,
                              void* d_out, int out_size, void* d_ws, size_t ws_size,
                              hipStream_t stream) {
    const float* q  = (const float*)d_in[0];
    const float* k  = (const float*)d_in[1];
    const float* Wq = (const float*)d_in[2];
    const float* Wk = (const float*)d_in[3];
    const float* Wv = (const float*)d_in[4];
    const float* Wp = (const float*)d_in[5];
    float* out = (float*)d_out;

    const size_t sz_q = (size_t)C_ * NQ_ * B_ * E_;
    const size_t sz_k = (size_t)C_ * NK_ * B_ * E_;
    short* wsq = (short*)d_ws;
    short* wsk = wsq + sz_q;
    short* wsv = wsk + sz_k;
    short* wso = wsv + sz_k;

    qkv_proj_kernel<<<dim3(640), dim3(512), 0, stream>>>(q, k, Wq, Wk, Wv, wsq, wsk, wsv);
    attn_kernel<<<dim3(2048), dim3(256), 0, stream>>>(wsq, wsk, wsv, wso);
    out_proj_kernel<<<dim3(512), dim3(256), 0, stream>>>(wso, Wp, out);
}